// Round 4
// baseline (443.647 us; speedup 1.0000x reference)
//
#include <hip/hip_runtime.h>
#include <math.h>

// ---------------- problem constants ----------------
constexpr int NFFT  = 256;
constexpr int HOP   = 64;
constexpr int NBIN  = 129;          // rfft bins
constexpr int NB    = 8;            // batch
constexpr int LMIX  = 65536;
constexpr int LAUX  = 262144;
constexpr int TM    = 1025;         // mix frames
constexpr int TA    = 4097;         // aux frames
constexpr int TROWS = 4175;         // aux frames + zero pad (78)
constexpr int HS    = 126;
constexpr int W     = 26;           // windows
constexpr int NJOBS = NB * W;       // 208
constexpr int NVAL  = TM * NBIN;    // 132225 values per (b,w)
constexpr int KMED  = (NVAL - 1) / 2; // 66112
constexpr int CHUNKS = 8;           // blocks per job in sim passes

// ---------------- workspace layout (bytes) ----------------
constexpr size_t MIXN_OFF  = 0;
constexpr size_t MIXN_BYTES = (size_t)NB * TM * NBIN * sizeof(float2);      // 8,462,400
constexpr size_t AUXN_OFF  = MIXN_OFF + MIXN_BYTES;
constexpr size_t AUXN_BYTES = (size_t)NB * TROWS * NBIN * sizeof(float2);   // 34,468,800
constexpr size_t HIST_OFF  = AUXN_OFF + AUXN_BYTES;
constexpr size_t HIST_BYTES = (size_t)NJOBS * CHUNKS * 2048 * 4;            // 13,631,488
constexpr size_t CAND_OFF  = HIST_OFF + HIST_BYTES;
constexpr size_t CAND_BYTES = (size_t)NJOBS * NVAL * 4;                     // 110,011,200 (worst case)
constexpr size_t TW_OFF    = CAND_OFF + CAND_BYTES;
constexpr size_t TW_BYTES  = 256 * sizeof(float2);
constexpr size_t NAN_OFF   = TW_OFF + TW_BYTES;
constexpr size_t NCAND_OFF = NAN_OFF + 832;
constexpr size_t SELBIN_OFF= NCAND_OFF + 832;
constexpr size_t KREM_OFF  = SELBIN_OFF + 832;
constexpr size_t MED_OFF   = KREM_OFF + 832;
constexpr size_t BEST_OFF  = MED_OFF + 832;
// total ~166.7 MB < 256 MiB ws

// ---------------- twiddle table + counter zeroing (replaces hipMemsetAsync) ----------------
__global__ void build_table(float2* __restrict__ tw, unsigned* __restrict__ nanC,
                            unsigned* __restrict__ ncand)
{
    int i = threadIdx.x;
    double ang = (double)i * (-2.0 * 3.14159265358979323846 / 256.0);
    tw[i] = make_float2((float)cos(ang), (float)sin(ang));
    if (i < NJOBS) { nanC[i] = 0u; ncand[i] = 0u; }
}

// ---------------- STFT via Cooley-Tukey 256 = 16 x 16 ----------------
// X[k] = sum_{n1=0..15} dk^{n1} * Y[n1][k mod 16],  dk = e^{-2pi i k/256}
// NORM: write X/|X| (NaN where |X|=0 or padded row) — feeds the sim passes.
template<int FPB, bool NORM>
__global__ void stft_fft(const float* __restrict__ x, const float2* __restrict__ twg,
                         int L, int Tframes, int Trows, float2* __restrict__ out)
{
    constexpr int NX = 64 * (FPB - 1) + NFFT;   // shared sample span (448 for FPB=4)
    __shared__ float  xs[NX];
    __shared__ float2 Y[FPB][16][16];
    __shared__ float2 cis16[16];

    const int tid = threadIdx.x;
    const int b   = blockIdx.y;
    const int f0  = blockIdx.x * FPB;

    if (tid < 16) cis16[tid] = twg[(16 * tid) & 255];

    for (int i = tid; i < NX; i += 256) {
        int j = f0 * HOP + i - 128;
        if (j < 0) j = -j;
        if (j >= L) j = 2 * L - 2 - j;
        xs[i] = x[(size_t)b * L + j];
    }
    __syncthreads();

    const int n1 = (tid >> 4) & 15;
    const int r  = tid & 15;
    #pragma unroll
    for (int f = 0; f < FPB; ++f) {
        float re = 0.f, im = 0.f;
        int idx = 0;
        #pragma unroll
        for (int n2 = 0; n2 < 16; ++n2) {
            float  v = xs[f * HOP + n1 + 16 * n2];
            float2 t = cis16[idx];
            re = fmaf(v, t.x, re);
            im = fmaf(v, t.y, im);
            idx = (idx + r) & 15;
        }
        Y[f][n1][r] = make_float2(re, im);
    }
    __syncthreads();

    const float QNAN = __int_as_float(0x7FC00000);
    for (int jj = tid; jj < FPB * NBIN; jj += 256) {
        int f  = jj / NBIN;
        int k  = jj - f * NBIN;
        int fr = f0 + f;
        if (fr >= Trows) continue;
        float2 o;
        if (fr < Tframes) {
            float2 dk = twg[k];
            float tr = 1.f, ti = 0.f;
            float ar = 0.f, ai = 0.f;
            #pragma unroll
            for (int s = 0; s < 16; ++s) {
                float2 y = Y[f][s][k & 15];
                ar = fmaf(tr, y.x, ar); ar = fmaf(-ti, y.y, ar);
                ai = fmaf(tr, y.y, ai); ai = fmaf( ti, y.x, ai);
                float nr = tr * dk.x - ti * dk.y;
                ti = fmaf(tr, dk.y, ti * dk.x);
                tr = nr;
            }
            if (NORM) {
                float inv = rsqrtf(ar * ar + ai * ai);   // |X|=0 -> inf -> NaN, as desired
                o = make_float2(ar * inv, ai * inv);
            } else {
                o = make_float2(ar, ai);
            }
        } else {
            o = NORM ? make_float2(QNAN, QNAN) : make_float2(0.f, 0.f);
        }
        out[((size_t)b * Trows + fr) * NBIN + k] = o;
    }
}

// ---------------- sortable key flip ----------------
__device__ __forceinline__ unsigned flip_key(float s) {
    unsigned u = __float_as_uint(s);
    return (u & 0x80000000u) ? ~u : (u | 0x80000000u);
}

// linear quantization of s in [-1,1] to 2048 bins; NaN -> 2047 (matches jnp.sort NaN-last)
__device__ __forceinline__ unsigned qbin(float s) {
    if (!(s == s)) return 2047u;
    int bq = (int)floorf(fmaf(s, 1024.f, 1024.f));
    bq = max(0, min(2047, bq));
    return (unsigned)bq;
}

// ---------------- PASS A: linear-bin histogram + NaN count ----------------
__global__ void sim_hist(const float2* __restrict__ mixN, const float2* __restrict__ auxN,
                         unsigned* __restrict__ hist, unsigned* __restrict__ nanCnt)
{
    constexpr int NCOPY   = 2;
    constexpr int HSTRIDE = 2049;                 // bank-offset copies
    __shared__ unsigned lh[NCOPY * HSTRIDE];      // 16,392 B -> 8 blocks/CU
    const int tid   = threadIdx.x;
    const int chunk = blockIdx.x;
    const int job   = blockIdx.y;
    const int b = job / W;
    const int w = job - b * W;
    unsigned* lhc = lh + ((tid >> 4) & (NCOPY - 1)) * HSTRIDE;

    for (int i = tid; i < NCOPY * HSTRIDE; i += 256) lh[i] = 0;
    __syncthreads();

    unsigned localnan = 0;
    const float2* mrow = mixN + (size_t)b * TM * NBIN;
    const float2* arow = auxN + ((size_t)b * TROWS + (size_t)w * HS) * NBIN;

    const int pad = b & 1;
    const int lim = pad + ((NVAL - pad) & ~1);

    for (int i = pad + (chunk * 256 + tid) * 2; i < lim; i += CHUNKS * 512) {
        float4 mv = *reinterpret_cast<const float4*>(mrow + i);
        float4 av = *reinterpret_cast<const float4*>(arow + i);
        float s0 = fmaf(mv.x, av.x, mv.y * av.y);
        float s1 = fmaf(mv.z, av.z, mv.w * av.w);
        if (!(s0 == s0)) localnan++;
        if (!(s1 == s1)) localnan++;
        atomicAdd(&lhc[qbin(s0)], 1u);
        atomicAdd(&lhc[qbin(s1)], 1u);
    }
    if (chunk == 0 && tid == 0) {                 // the one leftover scalar element
        int ie = pad ? 0 : NVAL - 1;
        float2 m = mrow[ie];
        float2 a = arow[ie];
        float s = fmaf(m.x, a.x, m.y * a.y);
        if (!(s == s)) localnan++;
        atomicAdd(&lhc[qbin(s)], 1u);
    }
    __syncthreads();

    unsigned* gh = hist + ((size_t)job * CHUNKS + chunk) * 2048;
    for (int i = tid; i < 2048; i += 256) gh[i] = lh[i] + lh[HSTRIDE + i];
    if (localnan) atomicAdd(&nanCnt[job], localnan);
}

// ---------------- scan: find linear bin containing rank KMED ----------------
__global__ void scan_bins(const unsigned* __restrict__ hist, unsigned* __restrict__ selbin,
                          unsigned* __restrict__ krem)
{
    constexpr int PER = 8;
    __shared__ unsigned psum[256];
    __shared__ unsigned selseg;
    __shared__ unsigned selbase;
    const int tid = threadIdx.x;
    const int job = blockIdx.x;
    const unsigned* h = hist + (size_t)job * CHUNKS * 2048;

    unsigned bins[PER];
    unsigned s = 0;
    #pragma unroll
    for (int i = 0; i < PER; ++i) {
        unsigned v = 0;
        int bin = tid * PER + i;
        #pragma unroll
        for (int c = 0; c < CHUNKS; ++c) v += h[(size_t)c * 2048 + bin];
        bins[i] = v; s += v;
    }
    psum[tid] = s;
    __syncthreads();

    const unsigned target = (unsigned)KMED;
    if (tid == 0) {
        unsigned cum = 0; unsigned seg = 255, base = 0;
        for (int t2 = 0; t2 < 256; ++t2) {
            if (cum + psum[t2] > target) { seg = t2; base = cum; break; }
            cum += psum[t2];
        }
        selseg = seg; selbase = base;
    }
    __syncthreads();

    if (tid == (int)selseg) {
        unsigned cum = selbase;
        #pragma unroll
        for (int i = 0; i < PER; ++i) {
            if (cum + bins[i] > target) {
                selbin[job] = (unsigned)(tid * PER + i);
                krem[job]   = target - cum;
                break;
            }
            cum += bins[i];
        }
    }
}

// ---------------- PASS B: recompute sim, compact selected-bin keys ----------------
__global__ void sim_compact(const float2* __restrict__ mixN, const float2* __restrict__ auxN,
                            const unsigned* __restrict__ selbin, unsigned* __restrict__ cand,
                            unsigned* __restrict__ ncand)
{
    const int tid   = threadIdx.x;
    const int chunk = blockIdx.x;
    const int job   = blockIdx.y;
    const int b = job / W;
    const int w = job - b * W;
    const unsigned sb = selbin[job];
    unsigned* candj  = cand + (size_t)job * NVAL;
    unsigned* ncandj = ncand + job;
    const int lane = tid & 63;

    const float2* mrow = mixN + (size_t)b * TM * NBIN;
    const float2* arow = auxN + ((size_t)b * TROWS + (size_t)w * HS) * NBIN;

    const int pad = b & 1;
    const int lim = pad + ((NVAL - pad) & ~1);

    for (int i = pad + (chunk * 256 + tid) * 2; i < lim; i += CHUNKS * 512) {
        float4 mv = *reinterpret_cast<const float4*>(mrow + i);
        float4 av = *reinterpret_cast<const float4*>(arow + i);
        float sv[2];
        sv[0] = fmaf(mv.x, av.x, mv.y * av.y);
        sv[1] = fmaf(mv.z, av.z, mv.w * av.w);
        #pragma unroll
        for (int u = 0; u < 2; ++u) {
            bool pred = (qbin(sv[u]) == sb);
            unsigned long long m = __ballot(pred);
            if (m) {
                int leader = __ffsll(m) - 1;
                unsigned base = 0;
                if (lane == leader) base = atomicAdd(ncandj, (unsigned)__popcll(m));
                base = (unsigned)__shfl((int)base, leader);
                if (pred) candj[base + __popcll(m & ((1ull << lane) - 1ull))] = flip_key(sv[u]);
            }
        }
    }
    if (chunk == 0 && tid == 0) {
        int ie = pad ? 0 : NVAL - 1;
        float2 m = mrow[ie];
        float2 a = arow[ie];
        float s = fmaf(m.x, a.x, m.y * a.y);
        if (qbin(s) == sb) {
            unsigned idx = atomicAdd(ncandj, 1u);
            candj[idx] = flip_key(s);
        }
    }
}

// ---------------- exact rank-select among candidates (3-phase radix over keys) --------
__global__ void select_kernel(const unsigned* __restrict__ cand, const unsigned* __restrict__ ncand,
                              const unsigned* __restrict__ krem, const unsigned* __restrict__ nanCnt,
                              float* __restrict__ med)
{
    __shared__ unsigned h[2048];
    __shared__ unsigned sh_pref;
    __shared__ unsigned sh_tgt;
    const int job = blockIdx.x;
    const int tid = threadIdx.x;
    const unsigned* c = cand + (size_t)job * NVAL;
    const unsigned n = ncand[job];
    unsigned pref = 0, tgt = krem[job];

    for (int ph = 0; ph < 3; ++ph) {
        for (int i = tid; i < 2048; i += 256) h[i] = 0;
        __syncthreads();
        for (unsigned i = tid; i < n; i += 256) {
            unsigned k = c[i];
            if (ph == 0) atomicAdd(&h[k >> 21], 1u);
            else if (ph == 1) { if ((k >> 21) == (pref >> 21)) atomicAdd(&h[(k >> 10) & 2047u], 1u); }
            else { if ((k >> 10) == (pref >> 10)) atomicAdd(&h[k & 1023u], 1u); }
        }
        __syncthreads();
        if (tid == 0) {
            const int nb = (ph == 2) ? 1024 : 2048;
            unsigned cum = 0;
            for (int bme = 0; bme < nb; ++bme) {
                unsigned cnt = h[bme];
                if (cum + cnt > tgt) {
                    if (ph == 0) pref = (unsigned)bme << 21;
                    else if (ph == 1) pref |= (unsigned)bme << 10;
                    else pref |= (unsigned)bme;
                    tgt -= cum;
                    break;
                }
                cum += cnt;
            }
            sh_pref = pref; sh_tgt = tgt;
        }
        __syncthreads();
        pref = sh_pref; tgt = sh_tgt;
    }

    if (tid == 0) {
        unsigned key = pref;
        unsigned u = (key & 0x80000000u) ? (key ^ 0x80000000u) : ~key;
        med[job] = (nanCnt[job] > 0u) ? -INFINITY : __uint_as_float(u);
    }
}

// ---------------- argmax over windows (first-wins) ----------------
__global__ void argmax_kernel(const float* __restrict__ med, int* __restrict__ best)
{
    int b = threadIdx.x;
    if (b < NB) {
        float mx = -INFINITY; int bi = 0;
        for (int w = 0; w < W; ++w) {
            float v = med[b * W + w];
            if (v > mx) { mx = v; bi = w; }
        }
        best[b] = bi;
    }
}

// ---------------- recompute raw STFT for the selected window, write output ----------------
template<int FPB>
__global__ void gather_stft(const float* __restrict__ x, const float2* __restrict__ twg,
                            const int* __restrict__ best, float* __restrict__ out)
{
    constexpr int NX = 64 * (FPB - 1) + NFFT;
    __shared__ float  xs[NX];
    __shared__ float2 Y[FPB][16][16];
    __shared__ float2 cis16[16];

    const int tid = threadIdx.x;
    const int b   = blockIdx.y;
    const int t0  = blockIdx.x * FPB;           // output row base (0..1024)
    const int fr0 = best[b] * HS + t0;          // aux frame base

    if (tid < 16) cis16[tid] = twg[(16 * tid) & 255];

    for (int i = tid; i < NX; i += 256) {
        int j = fr0 * HOP + i - 128;
        if (j < 0) j = -j;
        if (j >= LAUX) j = 2 * LAUX - 2 - j;
        j = max(0, min(LAUX - 1, j));           // safety clamp
        xs[i] = x[(size_t)b * LAUX + j];
    }
    __syncthreads();

    const int n1 = (tid >> 4) & 15;
    const int r  = tid & 15;
    #pragma unroll
    for (int f = 0; f < FPB; ++f) {
        float re = 0.f, im = 0.f;
        int idx = 0;
        #pragma unroll
        for (int n2 = 0; n2 < 16; ++n2) {
            float  v = xs[f * HOP + n1 + 16 * n2];
            float2 t = cis16[idx];
            re = fmaf(v, t.x, re);
            im = fmaf(v, t.y, im);
            idx = (idx + r) & 15;
        }
        Y[f][n1][r] = make_float2(re, im);
    }
    __syncthreads();

    for (int jj = tid; jj < FPB * NBIN; jj += 256) {
        int f  = jj / NBIN;
        int k  = jj - f * NBIN;
        int t  = t0 + f;
        if (t >= TM) continue;
        float ar = 0.f, ai = 0.f;
        if (fr0 + f < TA) {                     // padded rows are zero
            float2 dk = twg[k];
            float tr = 1.f, ti = 0.f;
            #pragma unroll
            for (int s = 0; s < 16; ++s) {
                float2 y = Y[f][s][k & 15];
                ar = fmaf(tr, y.x, ar); ar = fmaf(-ti, y.y, ar);
                ai = fmaf(tr, y.y, ai); ai = fmaf( ti, y.x, ai);
                float nr = tr * dk.x - ti * dk.y;
                ti = fmaf(tr, dk.y, ti * dk.x);
                tr = nr;
            }
        }
        size_t o = (size_t)t * NBIN + k;
        out[(size_t)(b * 2 + 0) * NVAL + o] = ar;
        out[(size_t)(b * 2 + 1) * NVAL + o] = ai;
    }
}

// ---------------- launch ----------------
extern "C" void kernel_launch(void* const* d_in, const int* in_sizes, int n_in,
                              void* d_out, int out_size, void* d_ws, size_t ws_size,
                              hipStream_t stream)
{
    const float* mix = (const float*)d_in[0];
    const float* aux = (const float*)d_in[1];
    float* out = (float*)d_out;
    char* ws = (char*)d_ws;

    float2*   mixN = (float2*)(ws + MIXN_OFF);
    float2*   auxN = (float2*)(ws + AUXN_OFF);
    unsigned* hist = (unsigned*)(ws + HIST_OFF);
    unsigned* cand = (unsigned*)(ws + CAND_OFF);
    float2*   twg  = (float2*)(ws + TW_OFF);
    unsigned* nanC = (unsigned*)(ws + NAN_OFF);
    unsigned* ncand= (unsigned*)(ws + NCAND_OFF);
    unsigned* selb = (unsigned*)(ws + SELBIN_OFF);
    unsigned* krem = (unsigned*)(ws + KREM_OFF);
    float*    med  = (float*)(ws + MED_OFF);
    int*      best = (int*)(ws + BEST_OFF);

    build_table<<<1, 256, 0, stream>>>(twg, nanC, ncand);

    constexpr int FPB = 4;
    stft_fft<FPB, true><<<dim3((TM + FPB - 1) / FPB, NB), 256, 0, stream>>>(mix, twg, LMIX, TM, TM, mixN);
    stft_fft<FPB, true><<<dim3((TROWS + FPB - 1) / FPB, NB), 256, 0, stream>>>(aux, twg, LAUX, TA, TROWS, auxN);

    sim_hist<<<dim3(CHUNKS, NJOBS), 256, 0, stream>>>(mixN, auxN, hist, nanC);
    scan_bins<<<NJOBS, 256, 0, stream>>>(hist, selb, krem);
    sim_compact<<<dim3(CHUNKS, NJOBS), 256, 0, stream>>>(mixN, auxN, selb, cand, ncand);
    select_kernel<<<NJOBS, 256, 0, stream>>>(cand, ncand, krem, nanC, med);

    argmax_kernel<<<1, 64, 0, stream>>>(med, best);
    gather_stft<FPB><<<dim3((TM + FPB - 1) / FPB, NB), 256, 0, stream>>>(aux, twg, best, out);
}

// Round 5
// 133.805 us; speedup vs baseline: 3.3156x; 3.3156x over previous
//
#include <hip/hip_runtime.h>
#include <math.h>

// ---------------- problem constants ----------------
constexpr int NFFT  = 256;
constexpr int HOP   = 64;
constexpr int NBIN  = 129;          // rfft bins
constexpr int NB    = 8;            // batch
constexpr int LMIX  = 65536;
constexpr int LAUX  = 262144;
constexpr int TM    = 1025;         // mix frames
constexpr int TA    = 4097;         // aux frames
constexpr int TROWS = 4175;         // aux frames + zero pad (78)
constexpr int HS    = 126;
constexpr int W     = 26;           // windows
constexpr int NJOBS = NB * W;       // 208
constexpr int NVAL  = TM * NBIN;    // 132225 values per (b,w)
constexpr int KMED  = (NVAL - 1) / 2; // 66112
constexpr int CHUNKS = 8;           // blocks per job in sim passes

// ---------------- workspace layout (bytes) ----------------
constexpr size_t MIXN_OFF  = 0;
constexpr size_t MIXN_BYTES = (size_t)NB * TM * NBIN * sizeof(float2);      // 8,462,400
constexpr size_t AUXN_OFF  = MIXN_OFF + MIXN_BYTES;
constexpr size_t AUXN_BYTES = (size_t)NB * TROWS * NBIN * sizeof(float2);   // 34,468,800
constexpr size_t HIST_OFF  = AUXN_OFF + AUXN_BYTES;
constexpr size_t HIST_BYTES = (size_t)NJOBS * CHUNKS * 2048 * 4;            // 13,631,488
constexpr size_t CAND_OFF  = HIST_OFF + HIST_BYTES;
constexpr size_t CAND_BYTES = (size_t)NJOBS * NVAL * 4;                     // 110,011,200 (worst case)
constexpr size_t TW_OFF    = CAND_OFF + CAND_BYTES;
constexpr size_t TW_BYTES  = 256 * sizeof(float2);
constexpr size_t NAN_OFF   = TW_OFF + TW_BYTES;
constexpr size_t NCAND_OFF = NAN_OFF + 832;
constexpr size_t SELBIN_OFF= NCAND_OFF + 832;
constexpr size_t KREM_OFF  = SELBIN_OFF + 832;
constexpr size_t MED_OFF   = KREM_OFF + 832;
constexpr size_t BEST_OFF  = MED_OFF + 832;
// total ~166.7 MB < 256 MiB ws

// ---------------- twiddle table + counter zeroing (replaces hipMemsetAsync) ----------------
__global__ void build_table(float2* __restrict__ tw, unsigned* __restrict__ nanC,
                            unsigned* __restrict__ ncand)
{
    int i = threadIdx.x;
    double ang = (double)i * (-2.0 * 3.14159265358979323846 / 256.0);
    tw[i] = make_float2((float)cos(ang), (float)sin(ang));
    if (i < NJOBS) { nanC[i] = 0u; ncand[i] = 0u; }
}

// ---------------- STFT via Cooley-Tukey 256 = 16 x 16 ----------------
// X[k] = sum_{n1=0..15} dk^{n1} * Y[n1][k mod 16],  dk = e^{-2pi i k/256}
// NORM: write X/|X| (NaN where |X|=0 or padded row) — feeds the sim passes.
template<int FPB, bool NORM>
__global__ void stft_fft(const float* __restrict__ x, const float2* __restrict__ twg,
                         int L, int Tframes, int Trows, float2* __restrict__ out)
{
    constexpr int NX = 64 * (FPB - 1) + NFFT;   // shared sample span (448 for FPB=4)
    __shared__ float  xs[NX];
    __shared__ float2 Y[FPB][16][16];
    __shared__ float2 cis16[16];

    const int tid = threadIdx.x;
    const int b   = blockIdx.y;
    const int f0  = blockIdx.x * FPB;

    if (tid < 16) cis16[tid] = twg[(16 * tid) & 255];

    for (int i = tid; i < NX; i += 256) {
        int j = f0 * HOP + i - 128;
        if (j < 0) j = -j;
        if (j >= L) j = 2 * L - 2 - j;
        xs[i] = x[(size_t)b * L + j];
    }
    __syncthreads();

    const int n1 = (tid >> 4) & 15;
    const int r  = tid & 15;
    #pragma unroll
    for (int f = 0; f < FPB; ++f) {
        float re = 0.f, im = 0.f;
        int idx = 0;
        #pragma unroll
        for (int n2 = 0; n2 < 16; ++n2) {
            float  v = xs[f * HOP + n1 + 16 * n2];
            float2 t = cis16[idx];
            re = fmaf(v, t.x, re);
            im = fmaf(v, t.y, im);
            idx = (idx + r) & 15;
        }
        Y[f][n1][r] = make_float2(re, im);
    }
    __syncthreads();

    const float QNAN = __int_as_float(0x7FC00000);
    for (int jj = tid; jj < FPB * NBIN; jj += 256) {
        int f  = jj / NBIN;
        int k  = jj - f * NBIN;
        int fr = f0 + f;
        if (fr >= Trows) continue;
        float2 o;
        if (fr < Tframes) {
            float2 dk = twg[k];
            float tr = 1.f, ti = 0.f;
            float ar = 0.f, ai = 0.f;
            #pragma unroll
            for (int s = 0; s < 16; ++s) {
                float2 y = Y[f][s][k & 15];
                ar = fmaf(tr, y.x, ar); ar = fmaf(-ti, y.y, ar);
                ai = fmaf(tr, y.y, ai); ai = fmaf( ti, y.x, ai);
                float nr = tr * dk.x - ti * dk.y;
                ti = fmaf(tr, dk.y, ti * dk.x);
                tr = nr;
            }
            if (NORM) {
                float inv = rsqrtf(ar * ar + ai * ai);   // |X|=0 -> inf -> NaN, as desired
                o = make_float2(ar * inv, ai * inv);
            } else {
                o = make_float2(ar, ai);
            }
        } else {
            o = NORM ? make_float2(QNAN, QNAN) : make_float2(0.f, 0.f);
        }
        out[((size_t)b * Trows + fr) * NBIN + k] = o;
    }
}

// ---------------- sortable key flip ----------------
__device__ __forceinline__ unsigned flip_key(float s) {
    unsigned u = __float_as_uint(s);
    return (u & 0x80000000u) ? ~u : (u | 0x80000000u);
}

// linear quantization of s in [-1,1] to 2048 bins; NaN -> 2047 (matches jnp.sort NaN-last)
__device__ __forceinline__ unsigned qbin(float s) {
    if (!(s == s)) return 2047u;
    int bq = (int)floorf(fmaf(s, 1024.f, 1024.f));
    bq = max(0, min(2047, bq));
    return (unsigned)bq;
}

// ---------------- parallel rank-find over 256*PER bins held in registers ----------------
// Each thread owns bins[0..PER) for bin indices [tid*PER, tid*PER+PER).
// Finds bin containing `target` (0-based rank) and the remainder within it.
// All threads return the same {out_bin, out_rem}. Requires total count > target.
template<int PER>
__device__ __forceinline__ void rank_find(const unsigned (&bins)[PER], unsigned target,
                                          unsigned& out_bin, unsigned& out_rem)
{
    __shared__ unsigned wtot[4];
    __shared__ unsigned result[2];
    const int tid  = threadIdx.x;
    const int lane = tid & 63;
    const int wid  = tid >> 6;

    unsigned st = 0;
    #pragma unroll
    for (int i = 0; i < PER; ++i) st += bins[i];

    // 64-lane inclusive scan
    unsigned inc = st;
    #pragma unroll
    for (int d = 1; d < 64; d <<= 1) {
        unsigned v = __shfl_up(inc, d);
        if (lane >= d) inc += v;
    }
    if (lane == 63) wtot[wid] = inc;
    __syncthreads();

    unsigned wbase = 0;
    for (int wme = 0; wme < wid; ++wme) wbase += wtot[wme];
    unsigned ex = wbase + inc - st;          // exclusive prefix for this thread
    bool pred = (ex <= target) && (target < ex + st);
    if (pred) {                              // exactly one thread
        unsigned cum = ex;
        #pragma unroll
        for (int i = 0; i < PER; ++i) {
            if (cum + bins[i] > target) {
                result[0] = (unsigned)(tid * PER + i);
                result[1] = target - cum;
                break;
            }
            cum += bins[i];
        }
    }
    __syncthreads();
    out_bin = result[0];
    out_rem = result[1];
}

// ---------------- PASS A: linear-bin histogram + NaN count ----------------
__global__ void sim_hist(const float2* __restrict__ mixN, const float2* __restrict__ auxN,
                         unsigned* __restrict__ hist, unsigned* __restrict__ nanCnt)
{
    constexpr int NCOPY   = 2;
    constexpr int HSTRIDE = 2049;                 // bank-offset copies
    __shared__ unsigned lh[NCOPY * HSTRIDE];      // 16,392 B -> 8 blocks/CU
    const int tid   = threadIdx.x;
    const int chunk = blockIdx.x;
    const int job   = blockIdx.y;
    const int b = job / W;
    const int w = job - b * W;
    unsigned* lhc = lh + ((tid >> 4) & (NCOPY - 1)) * HSTRIDE;

    for (int i = tid; i < NCOPY * HSTRIDE; i += 256) lh[i] = 0;
    __syncthreads();

    unsigned localnan = 0;
    const float2* mrow = mixN + (size_t)b * TM * NBIN;
    const float2* arow = auxN + ((size_t)b * TROWS + (size_t)w * HS) * NBIN;

    const int pad = b & 1;
    const int lim = pad + ((NVAL - pad) & ~1);

    for (int i = pad + (chunk * 256 + tid) * 2; i < lim; i += CHUNKS * 512) {
        float4 mv = *reinterpret_cast<const float4*>(mrow + i);
        float4 av = *reinterpret_cast<const float4*>(arow + i);
        float s0 = fmaf(mv.x, av.x, mv.y * av.y);
        float s1 = fmaf(mv.z, av.z, mv.w * av.w);
        if (!(s0 == s0)) localnan++;
        if (!(s1 == s1)) localnan++;
        atomicAdd(&lhc[qbin(s0)], 1u);
        atomicAdd(&lhc[qbin(s1)], 1u);
    }
    if (chunk == 0 && tid == 0) {                 // the one leftover scalar element
        int ie = pad ? 0 : NVAL - 1;
        float2 m = mrow[ie];
        float2 a = arow[ie];
        float s = fmaf(m.x, a.x, m.y * a.y);
        if (!(s == s)) localnan++;
        atomicAdd(&lhc[qbin(s)], 1u);
    }
    __syncthreads();

    unsigned* gh = hist + ((size_t)job * CHUNKS + chunk) * 2048;
    for (int i = tid; i < 2048; i += 256) gh[i] = lh[i] + lh[HSTRIDE + i];
    if (localnan) atomicAdd(&nanCnt[job], localnan);
}

// ---------------- scan: find linear bin containing rank KMED (parallel) ----------------
__global__ void scan_bins(const unsigned* __restrict__ hist, unsigned* __restrict__ selbin,
                          unsigned* __restrict__ krem)
{
    constexpr int PER = 8;
    const int tid = threadIdx.x;
    const int job = blockIdx.x;
    const unsigned* h = hist + (size_t)job * CHUNKS * 2048;

    unsigned bins[PER];
    #pragma unroll
    for (int i = 0; i < PER; ++i) {
        unsigned v = 0;
        int bin = tid * PER + i;
        #pragma unroll
        for (int c = 0; c < CHUNKS; ++c) v += h[(size_t)c * 2048 + bin];
        bins[i] = v;
    }

    unsigned sb, rem;
    rank_find<PER>(bins, (unsigned)KMED, sb, rem);
    if (tid == 0) { selbin[job] = sb; krem[job] = rem; }
}

// ---------------- PASS B: recompute sim, compact selected-bin keys ----------------
__global__ void sim_compact(const float2* __restrict__ mixN, const float2* __restrict__ auxN,
                            const unsigned* __restrict__ selbin, unsigned* __restrict__ cand,
                            unsigned* __restrict__ ncand)
{
    const int tid   = threadIdx.x;
    const int chunk = blockIdx.x;
    const int job   = blockIdx.y;
    const int b = job / W;
    const int w = job - b * W;
    const unsigned sb = selbin[job];
    unsigned* candj  = cand + (size_t)job * NVAL;
    unsigned* ncandj = ncand + job;
    const int lane = tid & 63;

    const float2* mrow = mixN + (size_t)b * TM * NBIN;
    const float2* arow = auxN + ((size_t)b * TROWS + (size_t)w * HS) * NBIN;

    const int pad = b & 1;
    const int lim = pad + ((NVAL - pad) & ~1);

    for (int i = pad + (chunk * 256 + tid) * 2; i < lim; i += CHUNKS * 512) {
        float4 mv = *reinterpret_cast<const float4*>(mrow + i);
        float4 av = *reinterpret_cast<const float4*>(arow + i);
        float sv[2];
        sv[0] = fmaf(mv.x, av.x, mv.y * av.y);
        sv[1] = fmaf(mv.z, av.z, mv.w * av.w);
        #pragma unroll
        for (int u = 0; u < 2; ++u) {
            bool pred = (qbin(sv[u]) == sb);
            unsigned long long m = __ballot(pred);
            if (m) {
                int leader = __ffsll(m) - 1;
                unsigned base = 0;
                if (lane == leader) base = atomicAdd(ncandj, (unsigned)__popcll(m));
                base = (unsigned)__shfl((int)base, leader);
                if (pred) candj[base + __popcll(m & ((1ull << lane) - 1ull))] = flip_key(sv[u]);
            }
        }
    }
    if (chunk == 0 && tid == 0) {
        int ie = pad ? 0 : NVAL - 1;
        float2 m = mrow[ie];
        float2 a = arow[ie];
        float s = fmaf(m.x, a.x, m.y * a.y);
        if (qbin(s) == sb) {
            unsigned idx = atomicAdd(ncandj, 1u);
            candj[idx] = flip_key(s);
        }
    }
}

// ---------------- exact rank-select among candidates (3-phase radix, parallel scan) -----
__global__ void select_kernel(const unsigned* __restrict__ cand, const unsigned* __restrict__ ncand,
                              const unsigned* __restrict__ krem, const unsigned* __restrict__ nanCnt,
                              float* __restrict__ med)
{
    __shared__ unsigned h[2048];
    const int job = blockIdx.x;
    const int tid = threadIdx.x;
    const unsigned* c = cand + (size_t)job * NVAL;
    const unsigned n = ncand[job];
    unsigned pref = 0, tgt = krem[job];

    for (int ph = 0; ph < 3; ++ph) {
        for (int i = tid; i < 2048; i += 256) h[i] = 0;
        __syncthreads();
        for (unsigned i = tid; i < n; i += 256) {
            unsigned k = c[i];
            if (ph == 0) atomicAdd(&h[k >> 21], 1u);
            else if (ph == 1) { if ((k >> 21) == (pref >> 21)) atomicAdd(&h[(k >> 10) & 2047u], 1u); }
            else { if ((k >> 10) == (pref >> 10)) atomicAdd(&h[k & 1023u], 1u); }  // bins 1024..2047 stay 0
        }
        __syncthreads();

        unsigned bins[8];
        #pragma unroll
        for (int i = 0; i < 8; ++i) bins[i] = h[tid * 8 + i];
        unsigned sb, rem;
        rank_find<8>(bins, tgt, sb, rem);

        if (ph == 0)      pref = sb << 21;
        else if (ph == 1) pref |= sb << 10;
        else              pref |= sb;
        tgt = rem;
        __syncthreads();   // protect h reuse vs. stragglers reading bins
    }

    if (tid == 0) {
        unsigned key = pref;
        unsigned u = (key & 0x80000000u) ? (key ^ 0x80000000u) : ~key;
        med[job] = (nanCnt[job] > 0u) ? -INFINITY : __uint_as_float(u);
    }
}

// ---------------- argmax over windows (first-wins) ----------------
__global__ void argmax_kernel(const float* __restrict__ med, int* __restrict__ best)
{
    int b = threadIdx.x;
    if (b < NB) {
        float mx = -INFINITY; int bi = 0;
        for (int w = 0; w < W; ++w) {
            float v = med[b * W + w];
            if (v > mx) { mx = v; bi = w; }
        }
        best[b] = bi;
    }
}

// ---------------- recompute raw STFT for the selected window, write output ----------------
template<int FPB>
__global__ void gather_stft(const float* __restrict__ x, const float2* __restrict__ twg,
                            const int* __restrict__ best, float* __restrict__ out)
{
    constexpr int NX = 64 * (FPB - 1) + NFFT;
    __shared__ float  xs[NX];
    __shared__ float2 Y[FPB][16][16];
    __shared__ float2 cis16[16];

    const int tid = threadIdx.x;
    const int b   = blockIdx.y;
    const int t0  = blockIdx.x * FPB;           // output row base (0..1024)
    const int fr0 = best[b] * HS + t0;          // aux frame base

    if (tid < 16) cis16[tid] = twg[(16 * tid) & 255];

    for (int i = tid; i < NX; i += 256) {
        int j = fr0 * HOP + i - 128;
        if (j < 0) j = -j;
        if (j >= LAUX) j = 2 * LAUX - 2 - j;
        j = max(0, min(LAUX - 1, j));           // safety clamp
        xs[i] = x[(size_t)b * LAUX + j];
    }
    __syncthreads();

    const int n1 = (tid >> 4) & 15;
    const int r  = tid & 15;
    #pragma unroll
    for (int f = 0; f < FPB; ++f) {
        float re = 0.f, im = 0.f;
        int idx = 0;
        #pragma unroll
        for (int n2 = 0; n2 < 16; ++n2) {
            float  v = xs[f * HOP + n1 + 16 * n2];
            float2 t = cis16[idx];
            re = fmaf(v, t.x, re);
            im = fmaf(v, t.y, im);
            idx = (idx + r) & 15;
        }
        Y[f][n1][r] = make_float2(re, im);
    }
    __syncthreads();

    for (int jj = tid; jj < FPB * NBIN; jj += 256) {
        int f  = jj / NBIN;
        int k  = jj - f * NBIN;
        int t  = t0 + f;
        if (t >= TM) continue;
        float ar = 0.f, ai = 0.f;
        if (fr0 + f < TA) {                     // padded rows are zero
            float2 dk = twg[k];
            float tr = 1.f, ti = 0.f;
            #pragma unroll
            for (int s = 0; s < 16; ++s) {
                float2 y = Y[f][s][k & 15];
                ar = fmaf(tr, y.x, ar); ar = fmaf(-ti, y.y, ar);
                ai = fmaf(tr, y.y, ai); ai = fmaf( ti, y.x, ai);
                float nr = tr * dk.x - ti * dk.y;
                ti = fmaf(tr, dk.y, ti * dk.x);
                tr = nr;
            }
        }
        size_t o = (size_t)t * NBIN + k;
        out[(size_t)(b * 2 + 0) * NVAL + o] = ar;
        out[(size_t)(b * 2 + 1) * NVAL + o] = ai;
    }
}

// ---------------- launch ----------------
extern "C" void kernel_launch(void* const* d_in, const int* in_sizes, int n_in,
                              void* d_out, int out_size, void* d_ws, size_t ws_size,
                              hipStream_t stream)
{
    const float* mix = (const float*)d_in[0];
    const float* aux = (const float*)d_in[1];
    float* out = (float*)d_out;
    char* ws = (char*)d_ws;

    float2*   mixN = (float2*)(ws + MIXN_OFF);
    float2*   auxN = (float2*)(ws + AUXN_OFF);
    unsigned* hist = (unsigned*)(ws + HIST_OFF);
    unsigned* cand = (unsigned*)(ws + CAND_OFF);
    float2*   twg  = (float2*)(ws + TW_OFF);
    unsigned* nanC = (unsigned*)(ws + NAN_OFF);
    unsigned* ncand= (unsigned*)(ws + NCAND_OFF);
    unsigned* selb = (unsigned*)(ws + SELBIN_OFF);
    unsigned* krem = (unsigned*)(ws + KREM_OFF);
    float*    med  = (float*)(ws + MED_OFF);
    int*      best = (int*)(ws + BEST_OFF);

    build_table<<<1, 256, 0, stream>>>(twg, nanC, ncand);

    constexpr int FPB = 4;
    stft_fft<FPB, true><<<dim3((TM + FPB - 1) / FPB, NB), 256, 0, stream>>>(mix, twg, LMIX, TM, TM, mixN);
    stft_fft<FPB, true><<<dim3((TROWS + FPB - 1) / FPB, NB), 256, 0, stream>>>(aux, twg, LAUX, TA, TROWS, auxN);

    sim_hist<<<dim3(CHUNKS, NJOBS), 256, 0, stream>>>(mixN, auxN, hist, nanC);
    scan_bins<<<NJOBS, 256, 0, stream>>>(hist, selb, krem);
    sim_compact<<<dim3(CHUNKS, NJOBS), 256, 0, stream>>>(mixN, auxN, selb, cand, ncand);
    select_kernel<<<NJOBS, 256, 0, stream>>>(cand, ncand, krem, nanC, med);

    argmax_kernel<<<1, 64, 0, stream>>>(med, best);
    gather_stft<FPB><<<dim3((TM + FPB - 1) / FPB, NB), 256, 0, stream>>>(aux, twg, best, out);
}